// Round 11
// baseline (70.051 us; speedup 1.0000x reference)
//
#include <hip/hip_runtime.h>
#include <hip/hip_fp16.h>
#include <math.h>

// Padded LDS index for FFT scratch: injective for e in [0,256) -> [0,271)
#define PIDX(e) ((e) + ((e) >> 4))

// Wave-local "sync": waves own disjoint LDS slices; same-wave DS ops are
// processed in order by the LDS pipe, so we only need a COMPILER fence.
#define WAVE_SYNC()                          \
    do {                                     \
        __builtin_amdgcn_wave_barrier();     \
        asm volatile("" ::: "memory");       \
    } while (0)

__device__ __forceinline__ float2 cadd(float2 a, float2 b) { return {a.x + b.x, a.y + b.y}; }
__device__ __forceinline__ float2 csub(float2 a, float2 b) { return {a.x - b.x, a.y - b.y}; }
__device__ __forceinline__ float2 cmul(float2 a, float2 b) {
    return {a.x * b.x - a.y * b.y, a.x * b.y + a.y * b.x};
}
__device__ __forceinline__ float2 shfl64(float2 v, int src) {
    return {__shfl(v.x, src), __shfl(v.y, src)};
}

// Radix-4 butterfly (DIF): d0..d3 from c0..c3.
#define BFLY4(c0, c1, c2, c3, d0, d1, d2, d3)            \
    {                                                    \
        float2 sa = cadd(c0, c2);                        \
        float2 sb = csub(c0, c2);                        \
        float2 sc = cadd(c1, c3);                        \
        float2 sd = {(c1).y - (c3).y, (c3).x - (c1).x}; \
        d0 = cadd(sa, sc);                               \
        d1 = cadd(sb, sd);                               \
        d2 = csub(sa, sc);                               \
        d3 = csub(sb, sd);                               \
    }

// Per-lane twiddle set for one stage (constant across all FFTs of the kernel).
struct Tw {
    float2 w1, w2, w3;
};
__device__ __forceinline__ Tw make_tw(int idx) {
    const float ang = -0.024543692606170259f * (float)idx;  // -(2pi/256)*idx
    float sy, cx;
    __sincosf(ang, &sy, &cx);
    Tw tw;
    tw.w1 = {cx, sy};
    tw.w2 = cmul(tw.w1, tw.w1);
    tw.w3 = cmul(tw.w2, tw.w1);
    return tw;
}

// Stage 0 (stride-64 partners, within-lane): registers -> LDS (natural order).
__device__ __forceinline__ void fft_stage0(float2 z0, float2 z1, float2 z2, float2 z3, float2* X,
                                           int t, const Tw& tw) {
    float2 d0, d1, d2, d3;
    BFLY4(z0, z1, z2, z3, d0, d1, d2, d3);
    const int ob = t << 2;
    X[PIDX(ob)] = d0;
    X[PIDX(ob + 1)] = cmul(tw.w1, d1);
    X[PIDX(ob + 2)] = cmul(tw.w2, d2);
    X[PIDX(ob + 3)] = cmul(tw.w3, d3);
    WAVE_SYNC();
}

// Middle stage (s=1: SH=2, s=2: SH=4), single LDS buffer: reads are always
// {t, t+64, t+128, t+192}; read-all -> fence -> write-all (same-wave DS order).
template <int SH>
__device__ __forceinline__ void fft_stage_mid(float2* X, int t, const Tw& tw) {
    float2 c0 = X[PIDX(t)];
    float2 c1 = X[PIDX(t + 64)];
    float2 c2 = X[PIDX(t + 128)];
    float2 c3 = X[PIDX(t + 192)];
    WAVE_SYNC();
    float2 d0, d1, d2, d3;
    BFLY4(c0, c1, c2, c3, d0, d1, d2, d3);
    const int mm = 1 << SH;
    const int jj = t >> SH;
    const int kk = t & (mm - 1);
    const int ob = kk + 4 * mm * jj;
    X[PIDX(ob)] = d0;
    X[PIDX(ob + mm)] = cmul(tw.w1, d1);
    X[PIDX(ob + 2 * mm)] = cmul(tw.w2, d2);
    X[PIDX(ob + 3 * mm)] = cmul(tw.w3, d3);
    WAVE_SYNC();
}

// Stage 3 (jj=0 -> identity twiddle): keep the result in registers.
// d_q = Z[t + 64q].
__device__ __forceinline__ void fft_stage3_reg(float2* X, int t, float2& d0, float2& d1,
                                               float2& d2, float2& d3) {
    float2 c0 = X[PIDX(t)];
    float2 c1 = X[PIDX(t + 64)];
    float2 c2 = X[PIDX(t + 128)];
    float2 c3 = X[PIDX(t + 192)];
    WAVE_SYNC();  // reads done before this buffer is overwritten by next stage0
    BFLY4(c0, c1, c2, c3, d0, d1, d2, d3);
}

// 16 strided dword loads: lane t gets element cols {t+64q} of rows r, r+1 for
// both inputs. Each instr reads 256B contiguous across the wave (coalesced).
__device__ __forceinline__ void load16(const float* __restrict__ abase,
                                       const float* __restrict__ sbase, int r, int t, float* a0,
                                       float* a1, float* s0, float* s1) {
#pragma unroll
    for (int q = 0; q < 4; ++q) {
        a0[q] = abase[(r << 8) + t + (q << 6)];
        a1[q] = abase[((r + 1) << 8) + t + (q << 6)];
        s0[q] = sbase[(r << 8) + t + (q << 6)];
        s1[q] = sbase[((r + 1) << 8) + t + (q << 6)];
    }
}

// FUSED kernel: one block per image job (pair x channel). Full 2D pipeline in
// LDS: 128 packed row-FFTs -> f16 spectrum [128 v][256 r] in LDS -> 128 col
// FFTs -> magnitude sum -> one float partial per image. No global intermediate.
// spec row stride 257 half2: row-phase write banks (t+2p)%32 (2-way, free),
// col-phase read banks consecutive (free).
// v=0 packs the two real columns (D[0], D[128]) as one complex column.
__global__ __launch_bounds__(512) void k_fused(const float* __restrict__ A,
                                               const float* __restrict__ P,
                                               const float* __restrict__ N,
                                               const int* __restrict__ negIdx,
                                               float* __restrict__ partial) {
    __shared__ __half2 spec[128 * 257];  // 131.6 KB
    __shared__ float2 Xb[8][272];        // 17.4 KB scratch
    __shared__ float wsum[8];

    const int img = blockIdx.x;
    const int pair = img / 3;
    const int ch = img - pair * 3;
    int i, jn;
    const float* S;
    if (pair < 32) {  // anchor-positive pairs: j == i
        i = pair;
        jn = pair;
        S = P;
    } else {  // anchor-negative pairs: j = neg_idx[i][k]
        const int t2 = pair - 32;
        i = t2 >> 1;
        jn = negIdx[(i << 1) + (t2 & 1)];
        S = N;
    }
    const float* abase = A + ((size_t)(i * 3 + ch) << 16);
    const float* sbase = S + ((size_t)(jn * 3 + ch) << 16);

    const int tid = threadIdx.x;
    const int w = tid >> 6;   // wave id [0,8)
    const int t = tid & 63;   // lane

    // Hoisted per-lane twiddles (constant for every FFT in this kernel).
    const Tw tw0 = make_tw(t);
    const Tw tw1 = make_tw(t & ~3);
    const Tw tw2 = make_tw(t & ~15);
    const int ridx = (64 - t) & 63;  // reversal shuffle index

    // ---- Row phase: 128 packed row-FFTs (two real rows per complex FFT) ----
    float pa0[4], pa1[4], ps0[4], ps1[4];
    load16(abase, sbase, 2 * w, t, pa0, pa1, ps0, ps1);

    for (int it = 0; it < 16; ++it) {
        const int p = it * 8 + w;  // packed-FFT index [0,128); rows (2p, 2p+1)
        float2 z[4];
#pragma unroll
        for (int q = 0; q < 4; ++q) z[q] = {pa0[q] - ps0[q], pa1[q] - ps1[q]};
        // prefetch next iteration's rows; flies under the whole FFT
        if (it < 15) load16(abase, sbase, 2 * ((it + 1) * 8 + w), t, pa0, pa1, ps0, ps1);
        fft_stage0(z[0], z[1], z[2], z[3], Xb[w], t, tw0);
        fft_stage_mid<2>(Xb[w], t, tw1);
        fft_stage_mid<4>(Xb[w], t, tw2);
        float2 d0, d1, d2, d3;  // d_q = Z[t + 64q]
        fft_stage3_reg(Xb[w], t, d0, d1, d2, d3);
        // Hermitian unpack (register/shuffle only):
        //   D_r[v] = 0.5*(Z[v] + conj(Z[-v]));  D_r1[v] = -0.5i*(Z[v] - conj(Z[-v]))
        const float2 m3 = shfl64(d3, ridx);  // Z[256-t] for t>=1
        const float2 m2 = shfl64(d2, ridx);  // Z[192-t] for t>=1
        const int r = 2 * p;
        if (t == 0) {
            // v=0 packs (D_r[0], D_r[128]) = (Re/Im Z[0], Re/Im Z[128])
            spec[r] = __floats2half2_rn(d0.x, d2.x);
            spec[r + 1] = __floats2half2_rn(d0.y, d2.y);
        } else {
            spec[t * 257 + r] = __floats2half2_rn(0.5f * (d0.x + m3.x), 0.5f * (d0.y - m3.y));
            spec[t * 257 + r + 1] =
                __floats2half2_rn(0.5f * (d0.y + m3.y), -0.5f * (d0.x - m3.x));
        }
        {  // v = t + 64;  m = Z[192-t] (lane 0: Z[192] = own d3)
            const int v = t + 64;
            const float2 mm2 = (t == 0) ? d3 : m2;
            spec[v * 257 + r] = __floats2half2_rn(0.5f * (d1.x + mm2.x), 0.5f * (d1.y - mm2.y));
            spec[v * 257 + r + 1] =
                __floats2half2_rn(0.5f * (d1.y + mm2.y), -0.5f * (d1.x - mm2.x));
        }
        WAVE_SYNC();  // Xb reuse next iter (wave-local hazard only)
    }

    __syncthreads();  // full spectrum in LDS

    // ---- Col phase: 128 column FFTs + magnitude accumulation ----
    float acc = 0.f;
    for (int it = 0; it < 16; ++it) {
        const int v = it * 8 + w;  // [0,128)
        float2 z[4];
#pragma unroll
        for (int q = 0; q < 4; ++q) z[q] = __half22float2(spec[v * 257 + t + (q << 6)]);
        fft_stage0(z[0], z[1], z[2], z[3], Xb[w], t, tw0);
        fft_stage_mid<2>(Xb[w], t, tw1);
        fft_stage_mid<4>(Xb[w], t, tw2);
        float2 d0, d1, d2, d3;  // d_q = W[t + 64q]
        fft_stage3_reg(Xb[w], t, d0, d1, d2, d3);
        float ssum = 0.f;
        if (v == 0) {  // wave-uniform rare path: needs W[-u]; LDS round trip
            Xb[w][PIDX(t)] = d0;
            Xb[w][PIDX(t + 64)] = d1;
            Xb[w][PIDX(t + 128)] = d2;
            Xb[w][PIDX(t + 192)] = d3;
            WAVE_SYNC();
#pragma unroll
            for (int q = 0; q < 4; ++q) {
                const int u = t + 64 * q;
                const float2 zu = Xb[w][PIDX(u)];
                const float2 zm = Xb[w][PIDX((256 - u) & 255)];
                // C_A[u] = 0.5(W[u]+conj(W[-u]));  C_B[u] = -0.5i(W[u]-conj(W[-u]))
                const float ax = 0.5f * (zu.x + zm.x), ay = 0.5f * (zu.y - zm.y);
                const float bx = 0.5f * (zu.y + zm.y), by = -0.5f * (zu.x - zm.x);
                ssum += sqrtf(ax * ax + ay * ay) + sqrtf(bx * bx + by * by);
            }
        } else {
            ssum = 2.f * (sqrtf(d0.x * d0.x + d0.y * d0.y) + sqrtf(d1.x * d1.x + d1.y * d1.y) +
                          sqrtf(d2.x * d2.x + d2.y * d2.y) + sqrtf(d3.x * d3.x + d3.y * d3.y));
        }
        acc += ssum;
        WAVE_SYNC();  // Xb fully consumed before next column's stage-0 writes
    }
#pragma unroll
    for (int off = 32; off; off >>= 1) acc += __shfl_down(acc, off);
    if (t == 0) wsum[w] = acc;
    __syncthreads();
    if (tid == 0) {
        float s = 0.f;
#pragma unroll
        for (int q = 0; q < 8; ++q) s += wsum[q];
        partial[img] = s;
    }
}

// partial[img], img = pair*3 + ch. pairSum[t] = sum of 3 channel partials.
// pairSum[0..31] = sum|FFT(a-p)| per i;  pairSum[32 + 2i + k] = sum|FFT(a_i - n_j)|
__global__ void k_final(const float* __restrict__ partial, float* __restrict__ out) {
    __shared__ float ps[96];
    const int t = threadIdx.x;  // 128 threads
    if (t < 96) ps[t] = partial[3 * t] + partial[3 * t + 1] + partial[3 * t + 2];
    __syncthreads();
    if (t < 64) {  // wave 0: t = 2i+k
        const float inv = 1.f / 196608.f;  // mean over C*H*W
        const float dap = ps[t >> 1] * inv;
        const float dan = ps[32 + t] * inv + 1e-7f;
        float val = dap / dan;
#pragma unroll
        for (int off = 32; off; off >>= 1) val += __shfl_down(val, off);
        if (t == 0) out[0] = val * (1.f / 64.f);  // / (MULTI_N_NUM * B)
    }
}

extern "C" void kernel_launch(void* const* d_in, const int* in_sizes, int n_in,
                              void* d_out, int out_size, void* d_ws, size_t ws_size,
                              hipStream_t stream) {
    const float* A = (const float*)d_in[0];
    const float* P = (const float*)d_in[1];
    const float* N = (const float*)d_in[2];
    const int* negIdx = (const int*)d_in[3];

    float* partial = (float*)d_ws;  // 288 floats

    k_fused<<<dim3(288), dim3(512), 0, stream>>>(A, P, N, negIdx, partial);
    k_final<<<1, 128, 0, stream>>>(partial, (float*)d_out);
}